// Round 7
// baseline (200.084 us; speedup 1.0000x reference)
//
#include <hip/hip_runtime.h>
#include <hip/hip_fp16.h>

// Ontomap: loss = sum((n2f@n_e - f_e)^2) + sum((m2f@m_e - f_e)^2)
// B = 1,048,576, D = 64.
// Round 7: (a) nci table converted to fp8-e4m3 (64 B/row = 1 line), fma table
// to fp16 (128 B/row) in d_ws each launch; (b) R2-style direct-to-fragment
// REGISTER gathers (no LDS, no barriers -- R2 proved this structure reaches
// ~6 TB/s issued, vs 4.3 for R6's DMA+drain); (c) R6's fused -I MFMA keeps
// the loss phase register-only. n/m matvec via mfma_f32_32x32x16_fp8_fp8,
// f subtraction via f16 -I MFMA into the same accumulators (C/D layout is
// shape-determined, dtype-independent).

typedef _Float16 half8 __attribute__((ext_vector_type(8)));
typedef __fp16  fp16x2 __attribute__((ext_vector_type(2)));
typedef float floatx16 __attribute__((ext_vector_type(16)));

#define NBLOCKS 1024
#define SAMPLES_PER_BLOCK 128   // 4 waves * 32 samples
#define NCI_ELEMS 9600000       // 150000 * 64
#define FMA_ELEMS 6400000       // 100000 * 64

__device__ inline half8 cvt8(float4 a, float4 b) {
    union { half8 h; fp16x2 h2[4]; } u;
    u.h2[0] = __builtin_amdgcn_cvt_pkrtz(a.x, a.y);
    u.h2[1] = __builtin_amdgcn_cvt_pkrtz(a.z, a.w);
    u.h2[2] = __builtin_amdgcn_cvt_pkrtz(b.x, b.y);
    u.h2[3] = __builtin_amdgcn_cvt_pkrtz(b.z, b.w);
    return u.h;
}

__device__ inline uint2 pack4(float4 v) {
    union { fp16x2 h2[2]; uint2 u; } p;
    p.h2[0] = __builtin_amdgcn_cvt_pkrtz(v.x, v.y);
    p.h2[1] = __builtin_amdgcn_cvt_pkrtz(v.z, v.w);
    return p.u;
}

// 8 fp32 -> 8 fp8-e4m3 bytes (k-ascending order).
__device__ inline uint2 pack8_fp8(float4 a, float4 b) {
    int lo = 0, hi = 0;
    lo = __builtin_amdgcn_cvt_pk_fp8_f32(a.x, a.y, lo, false);
    lo = __builtin_amdgcn_cvt_pk_fp8_f32(a.z, a.w, lo, true);
    hi = __builtin_amdgcn_cvt_pk_fp8_f32(b.x, b.y, hi, false);
    hi = __builtin_amdgcn_cvt_pk_fp8_f32(b.z, b.w, hi, true);
    uint2 r; r.x = (unsigned)lo; r.y = (unsigned)hi; return r;
}

// ---- streaming conversion: nci -> fp8, fma -> fp16, into workspace.
__global__ __launch_bounds__(256) void convert_kernel(
    const float4* __restrict__ nci, const float4* __restrict__ fma,
    uint2* __restrict__ nci8, uint2* __restrict__ fmah)
{
    const int stride = gridDim.x * blockDim.x;
    const int tid = blockIdx.x * blockDim.x + threadIdx.x;
    for (int i = tid; i < NCI_ELEMS / 8; i += stride)
        nci8[i] = pack8_fp8(nci[2 * i], nci[2 * i + 1]);
    for (int i = tid; i < FMA_ELEMS / 4; i += stride)
        fmah[i] = pack4(fma[i]);
}

// ---- main kernel: fp8 nci + fp16 fma, pure register dataflow.
__global__ __launch_bounds__(256, 2) void ontomap_kernel_q(
    const int* __restrict__ pos_n, const int* __restrict__ pos_m,
    const int* __restrict__ pos_f,
    const unsigned char* __restrict__ nci8, const __half* __restrict__ fmah,
    const float* __restrict__ n2f, const float* __restrict__ m2f,
    float* __restrict__ out, int iters)
{
    const int lane = threadIdx.x & 63;
    const int wave = threadIdx.x >> 6;
    const int l31  = lane & 31;
    const int hi   = lane >> 5;
    const int kbase = hi * 8;       // element offset within a 16-wide K step

    // B fragments (fp8): B[k][n] = M[n][k]; lane holds n = nt*32+l31,
    // k = t*16 + kbase + j (8 contiguous bytes).
    long Bn[2][4], Bm[2][4];
#pragma unroll
    for (int nt = 0; nt < 2; ++nt) {
#pragma unroll
        for (int t = 0; t < 4; ++t) {
            const float* p = n2f + (nt * 32 + l31) * 64 + t * 16 + kbase;
            uint2 pb = pack8_fp8(*(const float4*)p, *(const float4*)(p + 4));
            Bn[nt][t] = (long)(((unsigned long)pb.y << 32) | pb.x);
            const float* q = m2f + (nt * 32 + l31) * 64 + t * 16 + kbase;
            uint2 qb = pack8_fp8(*(const float4*)q, *(const float4*)(q + 4));
            Bm[nt][t] = (long)(((unsigned long)qb.y << 32) | qb.x);
        }
    }

    // -I fragments (f16) for the fused f subtraction: for k-step tp
    // (f-dim k' = tp*16 + kbase + j), tile nt = tp>>1 (n = nt*32 + l31):
    // element = -(k' == n); other (tp,nt) combos are all-zero -> skipped.
    half8 If[4];
#pragma unroll
    for (int tp = 0; tp < 4; ++tp) {
        const int n = (tp >> 1) * 32 + l31;
#pragma unroll
        for (int j = 0; j < 8; ++j) {
            const int kp = tp * 16 + kbase + j;
            If[tp][j] = (kp == n) ? (_Float16)(-1.0f) : (_Float16)(0.0f);
        }
    }

    float loss = 0.0f;

    int in_, im_, if_;
    {
        int s = blockIdx.x * SAMPLES_PER_BLOCK + wave * 32 + l31;
        in_ = pos_n[s]; im_ = pos_m[s]; if_ = pos_f[s];
    }

#pragma unroll 1
    for (int it = 0; it < iters; ++it) {
        const int in0 = in_, im0 = im_, if0 = if_;
        if (it + 1 < iters) {
            int s = ((it + 1) * NBLOCKS + blockIdx.x) * SAMPLES_PER_BLOCK
                    + wave * 32 + l31;
            in_ = pos_n[s]; im_ = pos_m[s]; if_ = pos_f[s];
        }

        // ---- direct-to-fragment gathers (all 12 loads independent).
        // A-frag (fp8): sample row = l31, k = t*16 + kbase + j -> byte
        // offset t*16 + hi*8 in the 64 B row; lanes l / l+32 cover 16 B
        // contiguous; one line per row per table.
        const unsigned char* pn = nci8 + (long)in0 * 64 + kbase;
        const unsigned char* pm = nci8 + (long)im0 * 64 + kbase;
        const __half* pf = fmah + (long)if0 * 64 + kbase;

        long An[4], Am[4];
        half8 Ff[4];
#pragma unroll
        for (int t = 0; t < 4; ++t) {
            An[t] = *(const long*)(pn + t * 16);
            Am[t] = *(const long*)(pm + t * 16);
            Ff[t] = *(const half8*)(pf + t * 16);
        }

        // ---- MFMA: h = e @ M^T (fp8), then -f via f16 -I into same acc.
        floatx16 aN0{}, aN1{}, aM0{}, aM1{};
#pragma unroll
        for (int t = 0; t < 4; ++t) {
            aN0 = __builtin_amdgcn_mfma_f32_32x32x16_fp8_fp8(An[t], Bn[0][t], aN0, 0, 0, 0);
            aN1 = __builtin_amdgcn_mfma_f32_32x32x16_fp8_fp8(An[t], Bn[1][t], aN1, 0, 0, 0);
            aM0 = __builtin_amdgcn_mfma_f32_32x32x16_fp8_fp8(Am[t], Bm[0][t], aM0, 0, 0, 0);
            aM1 = __builtin_amdgcn_mfma_f32_32x32x16_fp8_fp8(Am[t], Bm[1][t], aM1, 0, 0, 0);
        }
#pragma unroll
        for (int tp = 0; tp < 4; ++tp) {
            if (tp < 2) {
                aN0 = __builtin_amdgcn_mfma_f32_32x32x16_f16(Ff[tp], If[tp], aN0, 0, 0, 0);
                aM0 = __builtin_amdgcn_mfma_f32_32x32x16_f16(Ff[tp], If[tp], aM0, 0, 0, 0);
            } else {
                aN1 = __builtin_amdgcn_mfma_f32_32x32x16_f16(Ff[tp], If[tp], aN1, 0, 0, 0);
                aM1 = __builtin_amdgcn_mfma_f32_32x32x16_f16(Ff[tp], If[tp], aM1, 0, 0, 0);
            }
        }

        // ---- loss: pure register squares.
#pragma unroll
        for (int r = 0; r < 16; ++r) {
            loss = fmaf(aN0[r], aN0[r], loss);
            loss = fmaf(aN1[r], aN1[r], loss);
            loss = fmaf(aM0[r], aM0[r], loss);
            loss = fmaf(aM1[r], aM1[r], loss);
        }
    }

#pragma unroll
    for (int o = 32; o > 0; o >>= 1) loss += __shfl_xor(loss, o, 64);
    if (lane == 0) atomicAdd(out, loss);
}

// ---- fallback: fp32 tables direct (round-4 style), if ws too small.
#define ROW_BYTES 144
__global__ __launch_bounds__(256, 2) void ontomap_kernel_f32(
    const int* __restrict__ pos_n, const int* __restrict__ pos_m,
    const int* __restrict__ pos_f,
    const float* __restrict__ nci, const float* __restrict__ fma_emb,
    const float* __restrict__ n2f, const float* __restrict__ m2f,
    float* __restrict__ out, int iters)
{
    __shared__ char lds[4 * 2 * 32 * ROW_BYTES];

    const int lane = threadIdx.x & 63;
    const int wave = threadIdx.x >> 6;
    const int l31  = lane & 31;
    const int hi   = lane >> 5;
    const int kbase = hi * 8;
    const int srow   = lane >> 4;
    const int schunk = lane & 15;

    char* const nbase = lds + wave * (2 * 32 * ROW_BYTES);
    char* const mbase = nbase + 32 * ROW_BYTES;

    half8 Bn[2][4], Bm[2][4];
#pragma unroll
    for (int nt = 0; nt < 2; ++nt) {
#pragma unroll
        for (int t = 0; t < 4; ++t) {
            const float* p = n2f + (nt * 32 + l31) * 64 + t * 16 + kbase;
            Bn[nt][t] = cvt8(*(const float4*)p, *(const float4*)(p + 4));
            const float* q = m2f + (nt * 32 + l31) * 64 + t * 16 + kbase;
            Bm[nt][t] = cvt8(*(const float4*)q, *(const float4*)(q + 4));
        }
    }

    float loss = 0.0f;
    int in_, im_, if_;
    {
        int s = blockIdx.x * SAMPLES_PER_BLOCK + wave * 32 + l31;
        in_ = pos_n[s]; im_ = pos_m[s]; if_ = pos_f[s];
    }

#pragma unroll 1
    for (int it = 0; it < iters; ++it) {
        const int in0 = in_, im0 = im_, if0 = if_;
        if (it + 1 < iters) {
            int s = ((it + 1) * NBLOCKS + blockIdx.x) * SAMPLES_PER_BLOCK
                    + wave * 32 + l31;
            in_ = pos_n[s]; im_ = pos_m[s]; if_ = pos_f[s];
        }

#pragma unroll
        for (int i = 0; i < 8; ++i) {
            const int rl = i * 4 + srow;
            const int rn = __shfl(in0, rl, 64);
            float4 v = ((const float4*)(nci + (long)rn * 64))[schunk];
            *(uint2*)(nbase + rl * ROW_BYTES + schunk * 8) = pack4(v);
            const int rm = __shfl(im0, rl, 64);
            float4 w = ((const float4*)(nci + (long)rm * 64))[schunk];
            *(uint2*)(mbase + rl * ROW_BYTES + schunk * 8) = pack4(w);
        }
        asm volatile("" ::: "memory");

        floatx16 aN0{}, aN1{}, aM0{}, aM1{};
#pragma unroll
        for (int t = 0; t < 4; ++t) {
            half8 aF = *(const half8*)(nbase + l31 * ROW_BYTES + t * 32 + hi * 16);
            aN0 = __builtin_amdgcn_mfma_f32_32x32x16_f16(aF, Bn[0][t], aN0, 0, 0, 0);
            aN1 = __builtin_amdgcn_mfma_f32_32x32x16_f16(aF, Bn[1][t], aN1, 0, 0, 0);
            half8 bF = *(const half8*)(mbase + l31 * ROW_BYTES + t * 32 + hi * 16);
            aM0 = __builtin_amdgcn_mfma_f32_32x32x16_f16(bF, Bm[0][t], aM0, 0, 0, 0);
            aM1 = __builtin_amdgcn_mfma_f32_32x32x16_f16(bF, Bm[1][t], aM1, 0, 0, 0);
        }

#pragma unroll
        for (int r = 0; r < 16; ++r) {
            const int mrow = (r & 3) + 8 * (r >> 2) + 4 * hi;
            const int fid  = __shfl(if0, mrow, 64);
            const float* pf = fma_emb + (long)fid * 64 + l31;
            const float f0 = pf[0];
            const float f1 = pf[32];
            float d;
            d = aN0[r] - f0; loss = fmaf(d, d, loss);
            d = aM0[r] - f0; loss = fmaf(d, d, loss);
            d = aN1[r] - f1; loss = fmaf(d, d, loss);
            d = aM1[r] - f1; loss = fmaf(d, d, loss);
        }
    }

#pragma unroll
    for (int o = 32; o > 0; o >>= 1) loss += __shfl_xor(loss, o, 64);
    if (lane == 0) atomicAdd(out, loss);
}

extern "C" void kernel_launch(void* const* d_in, const int* in_sizes, int n_in,
                              void* d_out, int out_size, void* d_ws, size_t ws_size,
                              hipStream_t stream) {
    const int*   pos_n   = (const int*)d_in[0];
    const int*   pos_m   = (const int*)d_in[1];
    const int*   pos_f   = (const int*)d_in[2];
    const float* nci_emb = (const float*)d_in[3];
    const float* fma_emb = (const float*)d_in[4];
    const float* n2f_mat = (const float*)d_in[5];
    const float* m2f_mat = (const float*)d_in[6];
    float* out = (float*)d_out;

    const int B = in_sizes[0];
    const int iters = B / (NBLOCKS * SAMPLES_PER_BLOCK);  // 1,048,576 -> 8

    (void)hipMemsetAsync(out, 0, sizeof(float), stream);

    const size_t need = (size_t)NCI_ELEMS + (size_t)FMA_ELEMS * sizeof(__half);
    if (ws_size >= need) {
        unsigned char* nci8 = (unsigned char*)d_ws;
        __half* fmah = (__half*)(nci8 + NCI_ELEMS);   // 9,600,000 is 64B-aligned
        convert_kernel<<<2048, 256, 0, stream>>>(
            (const float4*)nci_emb, (const float4*)fma_emb,
            (uint2*)nci8, (uint2*)fmah);
        ontomap_kernel_q<<<NBLOCKS, 256, 0, stream>>>(
            pos_n, pos_m, pos_f, nci8, fmah, n2f_mat, m2f_mat, out, iters);
    } else {
        ontomap_kernel_f32<<<NBLOCKS, 256, 0, stream>>>(
            pos_n, pos_m, pos_f, nci_emb, fma_emb, n2f_mat, m2f_mat, out, iters);
    }
}

// Round 8
// 193.179 us; speedup vs baseline: 1.0357x; 1.0357x over previous
//
#include <hip/hip_runtime.h>
#include <hip/hip_fp16.h>

// Ontomap: loss = sum((n2f@n_e - f_e)^2) + sum((m2f@m_e - f_e)^2)
// B = 1,048,576, D = 64.
// Round 8: all tables fp8-e4m3 (64 B rows = 1 cache line each; 3 lines per
// sample total). Register-direct fragment gathers (no LDS). f subtraction
// fused as fp8 -I MFMA (exact for +-1). Accumulator tiles processed
// SEQUENTIALLY so only 16 AGPRs are live at a time -> ~105 total regs ->
// __launch_bounds__(256,4) gives 4 waves/EU (2x round 7 residency; the
// R5-R7 93-102us plateau with all pipes <25% busy is a concurrency limit
// on random line requests, not a bandwidth limit).

typedef _Float16 half8 __attribute__((ext_vector_type(8)));
typedef __fp16  fp16x2 __attribute__((ext_vector_type(2)));
typedef float floatx16 __attribute__((ext_vector_type(16)));

#define NBLOCKS 1024
#define SAMPLES_PER_BLOCK 128   // 4 waves * 32 samples
#define NCI_ELEMS 9600000       // 150000 * 64
#define FMA_ELEMS 6400000       // 100000 * 64

__device__ inline half8 cvt8(float4 a, float4 b) {
    union { half8 h; fp16x2 h2[4]; } u;
    u.h2[0] = __builtin_amdgcn_cvt_pkrtz(a.x, a.y);
    u.h2[1] = __builtin_amdgcn_cvt_pkrtz(a.z, a.w);
    u.h2[2] = __builtin_amdgcn_cvt_pkrtz(b.x, b.y);
    u.h2[3] = __builtin_amdgcn_cvt_pkrtz(b.z, b.w);
    return u.h;
}

__device__ inline uint2 pack4(float4 v) {
    union { fp16x2 h2[2]; uint2 u; } p;
    p.h2[0] = __builtin_amdgcn_cvt_pkrtz(v.x, v.y);
    p.h2[1] = __builtin_amdgcn_cvt_pkrtz(v.z, v.w);
    return p.u;
}

// 8 fp32 -> 8 fp8-e4m3 bytes (ascending order).
__device__ inline uint2 pack8_fp8(float4 a, float4 b) {
    int lo = 0, hi = 0;
    lo = __builtin_amdgcn_cvt_pk_fp8_f32(a.x, a.y, lo, false);
    lo = __builtin_amdgcn_cvt_pk_fp8_f32(a.z, a.w, lo, true);
    hi = __builtin_amdgcn_cvt_pk_fp8_f32(b.x, b.y, hi, false);
    hi = __builtin_amdgcn_cvt_pk_fp8_f32(b.z, b.w, hi, true);
    uint2 r; r.x = (unsigned)lo; r.y = (unsigned)hi; return r;
}

// ---- streaming conversion: both tables -> fp8, into workspace.
__global__ __launch_bounds__(256) void convert_kernel(
    const float4* __restrict__ nci, const float4* __restrict__ fma,
    uint2* __restrict__ nci8, uint2* __restrict__ fma8)
{
    const int stride = gridDim.x * blockDim.x;
    const int tid = blockIdx.x * blockDim.x + threadIdx.x;
    for (int i = tid; i < NCI_ELEMS / 8; i += stride)
        nci8[i] = pack8_fp8(nci[2 * i], nci[2 * i + 1]);
    for (int i = tid; i < FMA_ELEMS / 8; i += stride)
        fma8[i] = pack8_fp8(fma[2 * i], fma[2 * i + 1]);
}

// ---- main kernel: fp8 everything, register dataflow, sequential tiles.
__global__ __launch_bounds__(256, 4) void ontomap_kernel_q(
    const int* __restrict__ pos_n, const int* __restrict__ pos_m,
    const int* __restrict__ pos_f,
    const unsigned char* __restrict__ nci8, const unsigned char* __restrict__ fma8,
    const float* __restrict__ n2f, const float* __restrict__ m2f,
    float* __restrict__ out, int iters)
{
    const int lane = threadIdx.x & 63;
    const int wave = threadIdx.x >> 6;
    const int l31  = lane & 31;
    const int hi   = lane >> 5;
    const int kbase = hi * 8;       // element offset within a 16-wide K step

    // B fragments (fp8): B[k][n] = M[n][k]; lane holds n = nt*32+l31,
    // k = t*16 + kbase + j (8 contiguous bytes).
    long Bn[2][4], Bm[2][4];
#pragma unroll
    for (int nt = 0; nt < 2; ++nt) {
#pragma unroll
        for (int t = 0; t < 4; ++t) {
            const float* p = n2f + (nt * 32 + l31) * 64 + t * 16 + kbase;
            uint2 pb = pack8_fp8(*(const float4*)p, *(const float4*)(p + 4));
            Bn[nt][t] = (long)(((unsigned long)pb.y << 32) | pb.x);
            const float* q = m2f + (nt * 32 + l31) * 64 + t * 16 + kbase;
            uint2 qb = pack8_fp8(*(const float4*)q, *(const float4*)(q + 4));
            Bm[nt][t] = (long)(((unsigned long)qb.y << 32) | qb.x);
        }
    }

    // -I fragments (fp8, exact): for k-step tp (k' = tp*16 + kbase + j),
    // tile nt = tp>>1 (col n = nt*32 + l31): element = -(k' == n).
    long If8[4];
#pragma unroll
    for (int tp = 0; tp < 4; ++tp) {
        const int n = (tp >> 1) * 32 + l31;
        float4 a, b;
#pragma unroll
        for (int j = 0; j < 4; ++j) {
            ((float*)&a)[j] = (tp * 16 + kbase + j     == n) ? -1.0f : 0.0f;
            ((float*)&b)[j] = (tp * 16 + kbase + j + 4 == n) ? -1.0f : 0.0f;
        }
        uint2 ib = pack8_fp8(a, b);
        If8[tp] = (long)(((unsigned long)ib.y << 32) | ib.x);
    }

    float loss = 0.0f;

    int in_, im_, if_;
    {
        int s = blockIdx.x * SAMPLES_PER_BLOCK + wave * 32 + l31;
        in_ = pos_n[s]; im_ = pos_m[s]; if_ = pos_f[s];
    }

#pragma unroll 1
    for (int it = 0; it < iters; ++it) {
        const int in0 = in_, im0 = im_, if0 = if_;
        if (it + 1 < iters) {
            int s = ((it + 1) * NBLOCKS + blockIdx.x) * SAMPLES_PER_BLOCK
                    + wave * 32 + l31;
            in_ = pos_n[s]; im_ = pos_m[s]; if_ = pos_f[s];
        }

        // ---- 12 independent direct-to-fragment gathers (8 B/lane; lanes
        // l,l+32 cover 16 B contiguous; one 64 B line per row per table).
        const unsigned char* pn = nci8 + (long)in0 * 64 + kbase;
        const unsigned char* pm = nci8 + (long)im0 * 64 + kbase;
        const unsigned char* pf = fma8 + (long)if0 * 64 + kbase;

        long An[4], Am[4], Ff[4];
#pragma unroll
        for (int t = 0; t < 4; ++t) {
            An[t] = *(const long*)(pn + t * 16);
            Am[t] = *(const long*)(pm + t * 16);
            Ff[t] = *(const long*)(pf + t * 16);
        }

        // ---- sequential tiles: only one 16-reg accumulator live at a time.
        {   // n-loss, tile 0 (dims 0..31)
            floatx16 a{};
#pragma unroll
            for (int t = 0; t < 4; ++t)
                a = __builtin_amdgcn_mfma_f32_32x32x16_fp8_fp8(An[t], Bn[0][t], a, 0, 0, 0);
            a = __builtin_amdgcn_mfma_f32_32x32x16_fp8_fp8(Ff[0], If8[0], a, 0, 0, 0);
            a = __builtin_amdgcn_mfma_f32_32x32x16_fp8_fp8(Ff[1], If8[1], a, 0, 0, 0);
#pragma unroll
            for (int r = 0; r < 16; ++r) loss = fmaf(a[r], a[r], loss);
        }
        {   // n-loss, tile 1 (dims 32..63)
            floatx16 a{};
#pragma unroll
            for (int t = 0; t < 4; ++t)
                a = __builtin_amdgcn_mfma_f32_32x32x16_fp8_fp8(An[t], Bn[1][t], a, 0, 0, 0);
            a = __builtin_amdgcn_mfma_f32_32x32x16_fp8_fp8(Ff[2], If8[2], a, 0, 0, 0);
            a = __builtin_amdgcn_mfma_f32_32x32x16_fp8_fp8(Ff[3], If8[3], a, 0, 0, 0);
#pragma unroll
            for (int r = 0; r < 16; ++r) loss = fmaf(a[r], a[r], loss);
        }
        {   // m-loss, tile 0
            floatx16 a{};
#pragma unroll
            for (int t = 0; t < 4; ++t)
                a = __builtin_amdgcn_mfma_f32_32x32x16_fp8_fp8(Am[t], Bm[0][t], a, 0, 0, 0);
            a = __builtin_amdgcn_mfma_f32_32x32x16_fp8_fp8(Ff[0], If8[0], a, 0, 0, 0);
            a = __builtin_amdgcn_mfma_f32_32x32x16_fp8_fp8(Ff[1], If8[1], a, 0, 0, 0);
#pragma unroll
            for (int r = 0; r < 16; ++r) loss = fmaf(a[r], a[r], loss);
        }
        {   // m-loss, tile 1
            floatx16 a{};
#pragma unroll
            for (int t = 0; t < 4; ++t)
                a = __builtin_amdgcn_mfma_f32_32x32x16_fp8_fp8(Am[t], Bm[1][t], a, 0, 0, 0);
            a = __builtin_amdgcn_mfma_f32_32x32x16_fp8_fp8(Ff[2], If8[2], a, 0, 0, 0);
            a = __builtin_amdgcn_mfma_f32_32x32x16_fp8_fp8(Ff[3], If8[3], a, 0, 0, 0);
#pragma unroll
            for (int r = 0; r < 16; ++r) loss = fmaf(a[r], a[r], loss);
        }
    }

#pragma unroll
    for (int o = 32; o > 0; o >>= 1) loss += __shfl_xor(loss, o, 64);
    if (lane == 0) atomicAdd(out, loss);
}

// ---- fallback: fp32 tables with LDS staging (round-4 style), if ws too small.
#define ROW_BYTES 144
__global__ __launch_bounds__(256, 2) void ontomap_kernel_f32(
    const int* __restrict__ pos_n, const int* __restrict__ pos_m,
    const int* __restrict__ pos_f,
    const float* __restrict__ nci, const float* __restrict__ fma_emb,
    const float* __restrict__ n2f, const float* __restrict__ m2f,
    float* __restrict__ out, int iters)
{
    __shared__ char lds[4 * 2 * 32 * ROW_BYTES];

    const int lane = threadIdx.x & 63;
    const int wave = threadIdx.x >> 6;
    const int l31  = lane & 31;
    const int hi   = lane >> 5;
    const int kbase = hi * 8;
    const int srow   = lane >> 4;
    const int schunk = lane & 15;

    char* const nbase = lds + wave * (2 * 32 * ROW_BYTES);
    char* const mbase = nbase + 32 * ROW_BYTES;

    half8 Bn[2][4], Bm[2][4];
#pragma unroll
    for (int nt = 0; nt < 2; ++nt) {
#pragma unroll
        for (int t = 0; t < 4; ++t) {
            const float* p = n2f + (nt * 32 + l31) * 64 + t * 16 + kbase;
            Bn[nt][t] = cvt8(*(const float4*)p, *(const float4*)(p + 4));
            const float* q = m2f + (nt * 32 + l31) * 64 + t * 16 + kbase;
            Bm[nt][t] = cvt8(*(const float4*)q, *(const float4*)(q + 4));
        }
    }

    float loss = 0.0f;
    int in_, im_, if_;
    {
        int s = blockIdx.x * SAMPLES_PER_BLOCK + wave * 32 + l31;
        in_ = pos_n[s]; im_ = pos_m[s]; if_ = pos_f[s];
    }

#pragma unroll 1
    for (int it = 0; it < iters; ++it) {
        const int in0 = in_, im0 = im_, if0 = if_;
        if (it + 1 < iters) {
            int s = ((it + 1) * NBLOCKS + blockIdx.x) * SAMPLES_PER_BLOCK
                    + wave * 32 + l31;
            in_ = pos_n[s]; im_ = pos_m[s]; if_ = pos_f[s];
        }

#pragma unroll
        for (int i = 0; i < 8; ++i) {
            const int rl = i * 4 + srow;
            const int rn = __shfl(in0, rl, 64);
            float4 v = ((const float4*)(nci + (long)rn * 64))[schunk];
            *(uint2*)(nbase + rl * ROW_BYTES + schunk * 8) = pack4(v);
            const int rm = __shfl(im0, rl, 64);
            float4 w = ((const float4*)(nci + (long)rm * 64))[schunk];
            *(uint2*)(mbase + rl * ROW_BYTES + schunk * 8) = pack4(w);
        }
        asm volatile("" ::: "memory");

        floatx16 aN0{}, aN1{}, aM0{}, aM1{};
#pragma unroll
        for (int t = 0; t < 4; ++t) {
            half8 aF = *(const half8*)(nbase + l31 * ROW_BYTES + t * 32 + hi * 16);
            aN0 = __builtin_amdgcn_mfma_f32_32x32x16_f16(aF, Bn[0][t], aN0, 0, 0, 0);
            aN1 = __builtin_amdgcn_mfma_f32_32x32x16_f16(aF, Bn[1][t], aN1, 0, 0, 0);
            half8 bF = *(const half8*)(mbase + l31 * ROW_BYTES + t * 32 + hi * 16);
            aM0 = __builtin_amdgcn_mfma_f32_32x32x16_f16(bF, Bm[0][t], aM0, 0, 0, 0);
            aM1 = __builtin_amdgcn_mfma_f32_32x32x16_f16(bF, Bm[1][t], aM1, 0, 0, 0);
        }

#pragma unroll
        for (int r = 0; r < 16; ++r) {
            const int mrow = (r & 3) + 8 * (r >> 2) + 4 * hi;
            const int fid  = __shfl(if0, mrow, 64);
            const float* pf = fma_emb + (long)fid * 64 + l31;
            const float f0 = pf[0];
            const float f1 = pf[32];
            float d;
            d = aN0[r] - f0; loss = fmaf(d, d, loss);
            d = aM0[r] - f0; loss = fmaf(d, d, loss);
            d = aN1[r] - f1; loss = fmaf(d, d, loss);
            d = aM1[r] - f1; loss = fmaf(d, d, loss);
        }
    }

#pragma unroll
    for (int o = 32; o > 0; o >>= 1) loss += __shfl_xor(loss, o, 64);
    if (lane == 0) atomicAdd(out, loss);
}

extern "C" void kernel_launch(void* const* d_in, const int* in_sizes, int n_in,
                              void* d_out, int out_size, void* d_ws, size_t ws_size,
                              hipStream_t stream) {
    const int*   pos_n   = (const int*)d_in[0];
    const int*   pos_m   = (const int*)d_in[1];
    const int*   pos_f   = (const int*)d_in[2];
    const float* nci_emb = (const float*)d_in[3];
    const float* fma_emb = (const float*)d_in[4];
    const float* n2f_mat = (const float*)d_in[5];
    const float* m2f_mat = (const float*)d_in[6];
    float* out = (float*)d_out;

    const int B = in_sizes[0];
    const int iters = B / (NBLOCKS * SAMPLES_PER_BLOCK);  // 1,048,576 -> 8

    (void)hipMemsetAsync(out, 0, sizeof(float), stream);

    const size_t need = (size_t)NCI_ELEMS + (size_t)FMA_ELEMS;  // 16 MB
    if (ws_size >= need) {
        unsigned char* nci8 = (unsigned char*)d_ws;
        unsigned char* fma8 = nci8 + NCI_ELEMS;   // 9,600,000 is 64B-aligned
        convert_kernel<<<2048, 256, 0, stream>>>(
            (const float4*)nci_emb, (const float4*)fma_emb,
            (uint2*)nci8, (uint2*)fma8);
        ontomap_kernel_q<<<NBLOCKS, 256, 0, stream>>>(
            pos_n, pos_m, pos_f, nci8, fma8, n2f_mat, m2f_mat, out, iters);
    } else {
        ontomap_kernel_f32<<<NBLOCKS, 256, 0, stream>>>(
            pos_n, pos_m, pos_f, nci_emb, fma_emb, n2f_mat, m2f_mat, out, iters);
    }
}